// Round 12
// baseline (247.857 us; speedup 1.0000x reference)
//
#include <hip/hip_runtime.h>
#include <math.h>

#define B_ 8
#define N_ 1024
#define C_ 320
#define H_ 5
#define D_ 64
#define M_ (B_*N_)
#define TM 16

typedef unsigned short ushort_t;
typedef __attribute__((ext_vector_type(8))) short bf16x8;
typedef __attribute__((ext_vector_type(4))) float f32x4;

// fp32 -> bf16 RNE (manual, version-stable)
__device__ __forceinline__ ushort_t f2b(float f) {
  union { float f; unsigned u; } c; c.f = f;
  unsigned r = c.u + 0x7fffu + ((c.u >> 16) & 1u);
  return (ushort_t)(r >> 16);
}
__device__ __forceinline__ float b2f(ushort_t u) {
  union { float f; unsigned u; } c; c.u = ((unsigned)u) << 16;
  return c.f;
}
// force a block-uniform float into an SGPR
__device__ __forceinline__ float uni(float v) {
  union { float f; int i; } c; c.f = v;
  c.i = __builtin_amdgcn_readfirstlane(c.i);
  return c.f;
}

// ------- prep: weight bf16 conversion + LayerNorm, one launch -------
__global__ __launch_bounds__(256) void prep_kernel(
    const float* __restrict__ qkv_w, const float* __restrict__ proj_w,
    const float* __restrict__ x, const float* __restrict__ gamma,
    const float* __restrict__ beta,
    ushort_t* __restrict__ wqb, ushort_t* __restrict__ wpb,
    ushort_t* __restrict__ xnb) {
  int bid = blockIdx.x;
  int tid = threadIdx.x;
  if (bid < 200) {
    const float* src = bid < 150 ? qkv_w : proj_w;
    ushort_t* dst    = bid < 150 ? wqb   : wpb;
    int base = (bid < 150 ? bid : bid - 150) * 2048;
    int idx = base + tid*8;
    float4 x0 = *(const float4*)(src+idx);
    float4 x1 = *(const float4*)(src+idx+4);
    ushort_t pk[8] = {f2b(x0.x),f2b(x0.y),f2b(x0.z),f2b(x0.w),
                      f2b(x1.x),f2b(x1.y),f2b(x1.z),f2b(x1.w)};
    *(uint4*)(dst+idx) = *(const uint4*)pk;
  } else {
    int row = (bid - 200)*4 + (tid >> 6);
    int lane = tid & 63;
    const float* xr = x + (long)row * C_;
    float vals[5];
    float s = 0.f, ss = 0.f;
#pragma unroll
    for (int j = 0; j < 5; ++j) {
      float vv = xr[lane + 64*j];
      vals[j] = vv; s += vv; ss += vv*vv;
    }
#pragma unroll
    for (int o = 32; o > 0; o >>= 1) {
      s  += __shfl_xor(s, o, 64);
      ss += __shfl_xor(ss, o, 64);
    }
    float mean = s * (1.0f/C_);
    float var  = ss * (1.0f/C_) - mean*mean;
    float rstd = rsqrtf(var + 1e-5f);
    ushort_t* outr = xnb + (long)row * C_;
#pragma unroll
    for (int j = 0; j < 5; ++j) {
      int c = lane + 64*j;
      outr[c] = f2b((vals[j]-mean)*rstd*gamma[c] + beta[c]);
    }
  }
}

// ---------------- QKV GEMM via MFMA bf16: 128(M)x64(N) tile ----------------
__global__ __launch_bounds__(256) void qkvm_kernel(const ushort_t* __restrict__ xnb,
    const ushort_t* __restrict__ wqb, const float* __restrict__ bias,
    ushort_t* __restrict__ q, ushort_t* __restrict__ k, ushort_t* __restrict__ vt) {
  __shared__ __align__(16) ushort_t As[128][72];
  __shared__ __align__(16) ushort_t Bs[64][72];
  __shared__ __align__(16) ushort_t Vs[64][136];
  int j0 = blockIdx.x * 64;
  int m0 = blockIdx.y * 128;
  int tid = threadIdx.x;
  int lane = tid & 63, wv = tid >> 6;
  int l16 = lane & 15, qd = lane >> 4;
  f32x4 acc[2][4];
#pragma unroll
  for (int i=0;i<2;++i)
#pragma unroll
    for (int j=0;j<4;++j) acc[i][j] = (f32x4){0.f,0.f,0.f,0.f};
  for (int kk = 0; kk < C_; kk += 64) {
#pragma unroll
    for (int i = 0; i < 4; ++i) {
      int idx = tid + 256*i;
      int row = idx >> 3, c8 = (idx & 7) << 3;
      *(uint4*)&As[row][c8] = *(const uint4*)(xnb + (long)(m0+row)*C_ + kk + c8);
    }
    {
      int idx = tid;
      int row = idx >> 3, c8 = (idx & 7) << 3;
      *(uint4*)&Bs[row][c8] = *(const uint4*)(wqb + (long)(j0+row)*C_ + kk + c8);
      idx = tid + 256; row = idx >> 3; c8 = (idx & 7) << 3;
      *(uint4*)&Bs[row][c8] = *(const uint4*)(wqb + (long)(j0+row)*C_ + kk + c8);
    }
    __syncthreads();
#pragma unroll
    for (int kb = 0; kb < 2; ++kb) {
      int ko = kb*32 + qd*8;
      bf16x8 a0 = *(const bf16x8*)&As[wv*32 + l16][ko];
      bf16x8 a1 = *(const bf16x8*)&As[wv*32 + 16 + l16][ko];
#pragma unroll
      for (int ct = 0; ct < 4; ++ct) {
        bf16x8 b = *(const bf16x8*)&Bs[ct*16 + l16][ko];
        acc[0][ct] = __builtin_amdgcn_mfma_f32_16x16x32_bf16(a0, b, acc[0][ct], 0,0,0);
        acc[1][ct] = __builtin_amdgcn_mfma_f32_16x16x32_bf16(a1, b, acc[1][ct], 0,0,0);
      }
    }
    __syncthreads();
  }
  int three = j0 / 320;
  int rembase = j0 - three*320;
  if (three < 2) {
    ushort_t* dst = three == 0 ? q : k;
    float scale = three == 0 ? 0.125f : 1.0f;
#pragma unroll
    for (int rt = 0; rt < 2; ++rt)
#pragma unroll
      for (int ct = 0; ct < 4; ++ct) {
        int rem = rembase + ct*16 + l16;
        int h = rem >> 6, dd = rem & 63;
        float bi = bias[j0 + ct*16 + l16];
#pragma unroll
        for (int r = 0; r < 4; ++r) {
          int m = m0 + wv*32 + rt*16 + qd*4 + r;
          int b = m >> 10, n = m & (N_-1);
          dst[(((long)b*H_ + h)*N_ + n)*D_ + dd] = f2b((acc[rt][ct][r] + bi) * scale);
        }
      }
  } else {
    int h = rembase >> 6;
#pragma unroll
    for (int rt = 0; rt < 2; ++rt)
#pragma unroll
      for (int ct = 0; ct < 4; ++ct) {
        float bi = bias[j0 + ct*16 + l16];
#pragma unroll
        for (int r = 0; r < 4; ++r) {
          int col = wv*32 + rt*16 + qd*4 + r;
          Vs[ct*16 + l16][col] = f2b(acc[rt][ct][r] + bi);
        }
      }
    __syncthreads();
    int b = m0 >> 10, n0b = m0 & (N_-1);
#pragma unroll
    for (int i = 0; i < 4; ++i) {
      int idx = tid + 256*i;
      int row = idx >> 4, c8 = (idx & 15) << 3;
      *(uint4*)(vt + (((long)b*H_ + h)*D_ + row)*N_ + n0b + c8) = *(const uint4*)&Vs[row][c8];
    }
  }
}

// ---------------- score GEMM per (b,h): A-rows x B-cols, 128x128 / block ------
// Called with (A=k, B=q) -> output attnT[bh][key][query].
__global__ __launch_bounds__(256, 4) void qk_kernel(const ushort_t* __restrict__ amat,
    const ushort_t* __restrict__ bmat, ushort_t* __restrict__ attn) {
  __shared__ __align__(16) ushort_t Qs[128][72];
  __shared__ __align__(16) ushort_t Ks[128][72];
  int bh = blockIdx.z;
  int m0 = blockIdx.x * 128;
  int n0 = blockIdx.y * 128;
  int tid = threadIdx.x;
  int lane = tid & 63, wv = tid >> 6;
  int l16 = lane & 15, qd = lane >> 4;
  const ushort_t* qb = amat + ((long)bh*N_ + m0)*D_;
  const ushort_t* kb = bmat + ((long)bh*N_ + n0)*D_;
#pragma unroll
  for (int i = 0; i < 4; ++i) {
    int chunk = tid + 256*i;
    int row = chunk >> 3, c8 = (chunk & 7) << 3;
    *(uint4*)&Qs[row][c8] = *(const uint4*)(qb + (long)row*D_ + c8);
    *(uint4*)&Ks[row][c8] = *(const uint4*)(kb + (long)row*D_ + c8);
  }
  __syncthreads();
  f32x4 acc[2][8];
#pragma unroll
  for (int i=0;i<2;++i)
#pragma unroll
    for (int j=0;j<8;++j) acc[i][j] = (f32x4){0.f,0.f,0.f,0.f};
#pragma unroll
  for (int ks = 0; ks < 2; ++ks) {
    int k0 = ks*32 + qd*8;
    bf16x8 a0 = *(const bf16x8*)&Qs[wv*32 + l16][k0];
    bf16x8 a1 = *(const bf16x8*)&Qs[wv*32 + 16 + l16][k0];
#pragma unroll
    for (int ct = 0; ct < 8; ++ct) {
      bf16x8 b = *(const bf16x8*)&Ks[ct*16 + l16][k0];
      acc[0][ct] = __builtin_amdgcn_mfma_f32_16x16x32_bf16(a0, b, acc[0][ct], 0,0,0);
      acc[1][ct] = __builtin_amdgcn_mfma_f32_16x16x32_bf16(a1, b, acc[1][ct], 0,0,0);
    }
  }
  ushort_t* ob = attn + ((long)bh*N_ + m0 + wv*32)*N_ + n0;
#pragma unroll
  for (int rt = 0; rt < 2; ++rt)
#pragma unroll
    for (int r = 0; r < 4; ++r) {
      long rowoff = (long)(rt*16 + qd*4 + r)*N_;
#pragma unroll
      for (int ct = 0; ct < 8; ++ct)
        ob[rowoff + ct*16 + l16] = f2b(acc[rt][ct][r]);
    }
}

// ------- Fused separable blur + softmax + MFMA PV (v7: transposed input) -------
// attn is attnT[bh][key][query]. Thread m owns key-column m: its 22-query halo
// window is contiguous -> 4 aligned global b128 loads, unpacked ONCE (22 vs
// v5's 112), col-blur as in-register sliding window, centers free. No stage-1
// LDS staging / barrier. cb+cen -> LDS for the v5 stage-3/softmax/PV. LDS
// 80->68 KB (2 blocks/CU). XCD-aware block swizzle keeps adjacent-n0 blocks
// (which share 128B lines of attnT) on one XCD's L2.
#define CBS 1088
__global__ __launch_bounds__(1024) void bsp_kernel(
    const ushort_t* __restrict__ attn, const ushort_t* __restrict__ vt,
    ushort_t* __restrict__ aob) {
  __shared__ __align__(16) ushort_t cbP[16][CBS];    // col-blur (ghost gi=m+8) then P (swizzled)
  __shared__ __align__(16) ushort_t cen[16][1032];   // centers; later PV partials
  __shared__ float redm[16][2], reds[16][2], bsum[16];

  int l = blockIdx.x;
  int xcd = l & 7, tb = l >> 3;
  int n0 = ((xcd << 3) | (tb & 7)) * TM;   // XCD c owns n0-range [8c*16, 8c*16+128)
  int bh = tb >> 3;
  int h = bh % H_;
  int bb = bh / H_;
  int tid = threadIdx.x;
  int lane = tid & 63;

  float sigma = (float)(h + 1);
  float ei = -1.f / (2.f * sigma * sigma);
  float ga = expf(9.f*ei), gb = expf(4.f*ei), gc = expf(1.f*ei);
  float isum = 1.f / (2.f*(ga + gb + gc) + 1.f);
  float alpha = 0.1f * sigma;
  float u0 = uni(ga*isum), u1 = uni(gb*isum), u2 = uni(gc*isum), u3 = uni(isum);
  float au0 = uni(alpha*u0), au1 = uni(alpha*u1), au2 = uni(alpha*u2), au3 = uni(alpha*u3);
  const float uw[7] = {u0, u1, u2, u3, u2, u1, u0};
  const float aw[7] = {au0, au1, au2, au3, au2, au1, au0};

  // ---- stage A: per-thread contiguous column strip (queries n0-3..n0+18) ----
  const ushort_t* abm = attn + (long)bh*N_*N_ + (long)tid*N_;
  ushort_t xs[32];
  if (n0 >= TM && n0 <= N_ - 2*TM) {          // interior: n0 in [16, 992]
    const ushort_t* p = abm + n0 - 8;
    *(uint4*)&xs[0]  = *(const uint4*)(p);
    *(uint4*)&xs[8]  = *(const uint4*)(p + 8);
    *(uint4*)&xs[16] = *(const uint4*)(p + 16);
    *(uint4*)&xs[24] = *(const uint4*)(p + 24);
  } else if (n0 == 0) {
#pragma unroll
    for (int j = 0; j < 22; ++j) { int n = j < 3 ? 3 - j : j - 3; xs[5+j] = abm[n]; }
  } else {                                    // n0 == 1008
#pragma unroll
    for (int j = 0; j < 22; ++j) { int n = 1005 + j; n = n > 1023 ? 2046 - n : n; xs[5+j] = abm[n]; }
  }
  float xw[22];
#pragma unroll
  for (int j = 0; j < 22; ++j) xw[j] = b2f(xs[5 + j]);
#pragma unroll
  for (int r = 0; r < 16; ++r) {
    float v = 0.f;
#pragma unroll
    for (int tt = 0; tt < 7; ++tt) v += uw[tt] * xw[r + tt];
    ushort_t pv = f2b(v);
    cbP[r][tid + 8] = pv;
    cen[r][tid] = xs[8 + r];
    if (tid >= 1 && tid <= 3)       cbP[r][8 - tid] = pv;
    if (tid >= 1020 && tid <= 1022) cbP[r][2054 - tid] = pv;
  }
  __syncthreads();

  // ---- stage 3: row blur + center -> 16 logits in registers ----
  int o = tid >> 7;
  int cg = tid & 127;
  int m0c = cg << 3;
  float lgA[8], lgB[8];
#pragma unroll
  for (int half = 0; half < 2; ++half) {
    int r = 2*o + half;
    ushort_t cs[24];
    *(uint4*)&cs[0]  = *(const uint4*)&cbP[r][m0c];
    *(uint4*)&cs[8]  = *(const uint4*)&cbP[r][m0c + 8];
    *(uint4*)&cs[16] = *(const uint4*)&cbP[r][m0c + 16];
    float cf[24];
#pragma unroll
    for (int j = 0; j < 24; ++j) cf[j] = b2f(cs[j]);
    uint4 cv = *(const uint4*)&cen[r][m0c];
    const ushort_t* cvs = (const ushort_t*)&cv;
    float* lg = half ? lgB : lgA;
#pragma unroll
    for (int j = 0; j < 8; ++j) {
      float s = b2f(cvs[j]);
#pragma unroll
      for (int tt = 0; tt < 7; ++tt) s += aw[tt] * cf[5 + j + tt];
      lg[j] = s;
    }
  }

  // ---- softmax ----
  float lmA = lgA[0], lmB = lgB[0];
#pragma unroll
  for (int j = 1; j < 8; ++j) { lmA = fmaxf(lmA, lgA[j]); lmB = fmaxf(lmB, lgB[j]); }
#pragma unroll
  for (int off2 = 32; off2 > 0; off2 >>= 1) {
    lmA = fmaxf(lmA, __shfl_xor(lmA, off2, 64));
    lmB = fmaxf(lmB, __shfl_xor(lmB, off2, 64));
  }
  int wv2 = (tid >> 6) & 1;
  if (lane == 0) { redm[2*o][wv2] = lmA; redm[2*o+1][wv2] = lmB; }
  __syncthreads();    // cbP (cb) reads done -> safe to overwrite as P
  float bmA = fmaxf(redm[2*o][0], redm[2*o][1]);
  float bmB = fmaxf(redm[2*o+1][0], redm[2*o+1][1]);
  float smA = 0.f, smB = 0.f;
  unsigned pkA[4], pkB[4];
#pragma unroll
  for (int jj = 0; jj < 4; ++jj) {
    float eA0 = __expf(lgA[2*jj]   - bmA);
    float eA1 = __expf(lgA[2*jj+1] - bmA);
    float eB0 = __expf(lgB[2*jj]   - bmB);
    float eB1 = __expf(lgB[2*jj+1] - bmB);
    smA += eA0 + eA1; smB += eB0 + eB1;
    pkA[jj] = (unsigned)f2b(eA0) | ((unsigned)f2b(eA1) << 16);
    pkB[jj] = (unsigned)f2b(eB0) | ((unsigned)f2b(eB1) << 16);
  }
  *(uint4*)&cbP[2*o][((cg + 2*o) & 127) << 3]     = make_uint4(pkA[0], pkA[1], pkA[2], pkA[3]);
  *(uint4*)&cbP[2*o+1][((cg + 2*o+1) & 127) << 3] = make_uint4(pkB[0], pkB[1], pkB[2], pkB[3]);
#pragma unroll
  for (int off2 = 32; off2 > 0; off2 >>= 1) {
    smA += __shfl_xor(smA, off2, 64);
    smB += __shfl_xor(smB, off2, 64);
  }
  if (lane == 0) { reds[2*o][wv2] = smA; reds[2*o+1][wv2] = smB; }
  __syncthreads();                        // P + reds visible
  if (tid < 16) bsum[tid] = reds[tid][0] + reds[tid][1];

  // ---- PV via MFMA: out[16][64] = P[16][1024] @ V[1024][64] ----
  int wv = tid >> 6;
  int dt = wv & 3, kc = wv >> 2;
  int qd = lane >> 4, l16 = lane & 15;
  f32x4 pvacc = {0.f, 0.f, 0.f, 0.f};
  const ushort_t* vtb = vt + ((long)bh*D_ + dt*16 + l16)*N_;
#pragma unroll
  for (int s = 0; s < 8; ++s) {
    int g = kc*32 + s*4 + qd;
    bf16x8 afrag = *(const bf16x8*)&cbP[l16][((g + l16) & 127) << 3];
    bf16x8 bfrag = *(const bf16x8*)(vtb + (g << 3));
    pvacc = __builtin_amdgcn_mfma_f32_16x16x32_bf16(afrag, bfrag, pvacc, 0, 0, 0);
  }
  float* pvscr = (float*)&cen[0][0];      // cen dead after stage 3
  if (kc > 0) {
    *(f32x4*)(pvscr + ((kc-1)*4 + dt)*256 + lane*4) = pvacc;
  }
  __syncthreads();                        // partials + bsum visible
  if (kc == 0) {
#pragma unroll
    for (int j = 0; j < 3; ++j) {
      f32x4 oth = *(const f32x4*)(pvscr + (j*4 + dt)*256 + lane*4);
      pvacc += oth;
    }
#pragma unroll
    for (int r = 0; r < 4; ++r) {
      int row = qd*4 + r;
      aob[((long)(bb*N_ + n0 + row))*C_ + h*64 + dt*16 + l16] = f2b(pvacc[r] / bsum[row]);
    }
  }
}

// ---------------- proj GEMM via MFMA bf16: 128(M)x64(N) tile ----------------
__global__ __launch_bounds__(256) void projm_kernel(const ushort_t* __restrict__ aob,
    const ushort_t* __restrict__ wpb, const float* __restrict__ bias,
    float* __restrict__ out) {
  __shared__ __align__(16) ushort_t As[128][72];
  __shared__ __align__(16) ushort_t Bs[64][72];
  int j0 = blockIdx.x * 64;
  int m0 = blockIdx.y * 128;
  int tid = threadIdx.x;
  int lane = tid & 63, wv = tid >> 6;
  int l16 = lane & 15, qd = lane >> 4;
  f32x4 acc[2][4];
#pragma unroll
  for (int i=0;i<2;++i)
#pragma unroll
    for (int j=0;j<4;++j) acc[i][j] = (f32x4){0.f,0.f,0.f,0.f};
  for (int kk = 0; kk < C_; kk += 64) {
#pragma unroll
    for (int i = 0; i < 4; ++i) {
      int idx = tid + 256*i;
      int row = idx >> 3, c8 = (idx & 7) << 3;
      *(uint4*)&As[row][c8] = *(const uint4*)(aob + (long)(m0+row)*C_ + kk + c8);
    }
    {
      int idx = tid;
      int row = idx >> 3, c8 = (idx & 7) << 3;
      *(uint4*)&Bs[row][c8] = *(const uint4*)(wpb + (long)(j0+row)*C_ + kk + c8);
      idx = tid + 256; row = idx >> 3; c8 = (idx & 7) << 3;
      *(uint4*)&Bs[row][c8] = *(const uint4*)(wpb + (long)(j0+row)*C_ + kk + c8);
    }
    __syncthreads();
#pragma unroll
    for (int kb = 0; kb < 2; ++kb) {
      int ko = kb*32 + qd*8;
      bf16x8 a0 = *(const bf16x8*)&As[wv*32 + l16][ko];
      bf16x8 a1 = *(const bf16x8*)&As[wv*32 + 16 + l16][ko];
#pragma unroll
      for (int ct = 0; ct < 4; ++ct) {
        bf16x8 b = *(const bf16x8*)&Bs[ct*16 + l16][ko];
        acc[0][ct] = __builtin_amdgcn_mfma_f32_16x16x32_bf16(a0, b, acc[0][ct], 0,0,0);
        acc[1][ct] = __builtin_amdgcn_mfma_f32_16x16x32_bf16(a1, b, acc[1][ct], 0,0,0);
      }
    }
    __syncthreads();
  }
#pragma unroll
  for (int rt = 0; rt < 2; ++rt)
#pragma unroll
    for (int ct = 0; ct < 4; ++ct) {
      float bi = bias[j0 + ct*16 + l16];
#pragma unroll
      for (int r = 0; r < 4; ++r) {
        int m = m0 + wv*32 + rt*16 + qd*4 + r;
        out[(long)m*C_ + j0 + ct*16 + l16] = acc[rt][ct][r] + bi;
      }
    }
}

extern "C" void kernel_launch(void* const* d_in, const int* in_sizes, int n_in,
                              void* d_out, int out_size, void* d_ws, size_t ws_size,
                              hipStream_t stream) {
  const float* x      = (const float*)d_in[0];
  const float* ln_g   = (const float*)d_in[1];
  const float* ln_b   = (const float*)d_in[2];
  const float* qkv_w  = (const float*)d_in[3];
  const float* qkv_b  = (const float*)d_in[4];
  const float* proj_w = (const float*)d_in[5];
  const float* proj_b = (const float*)d_in[6];
  float* out = (float*)d_out;

  char* ws = (char*)d_ws;
  const long sz_bhnd = (long)B_*H_*N_*D_;   // 2,621,440
  ushort_t* xnb  = (ushort_t*)ws;                   ws += (long)M_*C_*2;
  ushort_t* aob  = (ushort_t*)ws;                   ws += (long)M_*C_*2;
  ushort_t* q    = (ushort_t*)ws;                   ws += sz_bhnd*2;
  ushort_t* k    = (ushort_t*)ws;                   ws += sz_bhnd*2;
  ushort_t* vt   = (ushort_t*)ws;                   ws += sz_bhnd*2;
  ushort_t* wqb  = (ushort_t*)ws;                   ws += (long)3*C_*C_*2;
  ushort_t* wpb  = (ushort_t*)ws;                   ws += (long)C_*C_*2;
  ushort_t* attn = (ushort_t*)ws;                   // attnT: [bh][key][query], 84 MB

  prep_kernel<<<2248, 256, 0, stream>>>(qkv_w, proj_w, x, ln_g, ln_b, wqb, wpb, xnb);
  qkvm_kernel<<<dim3(15, 64), 256, 0, stream>>>(xnb, wqb, qkv_b, q, k, vt);
  // A=k, B=q  ->  attnT[key][query]
  qk_kernel<<<dim3(8, 8, B_*H_), 256, 0, stream>>>(k, q, attn);
  bsp_kernel<<<dim3(2560), 1024, 0, stream>>>(attn, vt, aob);
  projm_kernel<<<dim3(5, 64), 256, 0, stream>>>(aob, wpb, proj_b, out);
}

// Round 13
// 196.886 us; speedup vs baseline: 1.2589x; 1.2589x over previous
//
#include <hip/hip_runtime.h>
#include <math.h>

#define B_ 8
#define N_ 1024
#define C_ 320
#define H_ 5
#define D_ 64
#define M_ (B_*N_)
#define TM 16

typedef unsigned short ushort_t;
typedef __attribute__((ext_vector_type(8))) short bf16x8;
typedef __attribute__((ext_vector_type(4))) float f32x4;

// fp32 -> bf16 RNE (manual, version-stable)
__device__ __forceinline__ ushort_t f2b(float f) {
  union { float f; unsigned u; } c; c.f = f;
  unsigned r = c.u + 0x7fffu + ((c.u >> 16) & 1u);
  return (ushort_t)(r >> 16);
}
__device__ __forceinline__ float b2f(ushort_t u) {
  union { float f; unsigned u; } c; c.u = ((unsigned)u) << 16;
  return c.f;
}
// force a block-uniform float into an SGPR
__device__ __forceinline__ float uni(float v) {
  union { float f; int i; } c; c.f = v;
  c.i = __builtin_amdgcn_readfirstlane(c.i);
  return c.f;
}

// ------- prep: weight bf16 conversion + LayerNorm, one launch -------
__global__ __launch_bounds__(256) void prep_kernel(
    const float* __restrict__ qkv_w, const float* __restrict__ proj_w,
    const float* __restrict__ x, const float* __restrict__ gamma,
    const float* __restrict__ beta,
    ushort_t* __restrict__ wqb, ushort_t* __restrict__ wpb,
    ushort_t* __restrict__ xnb) {
  int bid = blockIdx.x;
  int tid = threadIdx.x;
  if (bid < 200) {
    const float* src = bid < 150 ? qkv_w : proj_w;
    ushort_t* dst    = bid < 150 ? wqb   : wpb;
    int base = (bid < 150 ? bid : bid - 150) * 2048;
    int idx = base + tid*8;
    float4 x0 = *(const float4*)(src+idx);
    float4 x1 = *(const float4*)(src+idx+4);
    ushort_t pk[8] = {f2b(x0.x),f2b(x0.y),f2b(x0.z),f2b(x0.w),
                      f2b(x1.x),f2b(x1.y),f2b(x1.z),f2b(x1.w)};
    *(uint4*)(dst+idx) = *(const uint4*)pk;
  } else {
    int row = (bid - 200)*4 + (tid >> 6);
    int lane = tid & 63;
    const float* xr = x + (long)row * C_;
    float vals[5];
    float s = 0.f, ss = 0.f;
#pragma unroll
    for (int j = 0; j < 5; ++j) {
      float vv = xr[lane + 64*j];
      vals[j] = vv; s += vv; ss += vv*vv;
    }
#pragma unroll
    for (int o = 32; o > 0; o >>= 1) {
      s  += __shfl_xor(s, o, 64);
      ss += __shfl_xor(ss, o, 64);
    }
    float mean = s * (1.0f/C_);
    float var  = ss * (1.0f/C_) - mean*mean;
    float rstd = rsqrtf(var + 1e-5f);
    ushort_t* outr = xnb + (long)row * C_;
#pragma unroll
    for (int j = 0; j < 5; ++j) {
      int c = lane + 64*j;
      outr[c] = f2b((vals[j]-mean)*rstd*gamma[c] + beta[c]);
    }
  }
}

// ---------------- QKV GEMM via MFMA bf16: 128(M)x64(N) tile ----------------
__global__ __launch_bounds__(256) void qkvm_kernel(const ushort_t* __restrict__ xnb,
    const ushort_t* __restrict__ wqb, const float* __restrict__ bias,
    ushort_t* __restrict__ q, ushort_t* __restrict__ k, ushort_t* __restrict__ vt) {
  __shared__ __align__(16) ushort_t As[128][72];
  __shared__ __align__(16) ushort_t Bs[64][72];
  __shared__ __align__(16) ushort_t Vs[64][136];
  int j0 = blockIdx.x * 64;
  int m0 = blockIdx.y * 128;
  int tid = threadIdx.x;
  int lane = tid & 63, wv = tid >> 6;
  int l16 = lane & 15, qd = lane >> 4;
  f32x4 acc[2][4];
#pragma unroll
  for (int i=0;i<2;++i)
#pragma unroll
    for (int j=0;j<4;++j) acc[i][j] = (f32x4){0.f,0.f,0.f,0.f};
  for (int kk = 0; kk < C_; kk += 64) {
#pragma unroll
    for (int i = 0; i < 4; ++i) {
      int idx = tid + 256*i;
      int row = idx >> 3, c8 = (idx & 7) << 3;
      *(uint4*)&As[row][c8] = *(const uint4*)(xnb + (long)(m0+row)*C_ + kk + c8);
    }
    {
      int idx = tid;
      int row = idx >> 3, c8 = (idx & 7) << 3;
      *(uint4*)&Bs[row][c8] = *(const uint4*)(wqb + (long)(j0+row)*C_ + kk + c8);
      idx = tid + 256; row = idx >> 3; c8 = (idx & 7) << 3;
      *(uint4*)&Bs[row][c8] = *(const uint4*)(wqb + (long)(j0+row)*C_ + kk + c8);
    }
    __syncthreads();
#pragma unroll
    for (int kb = 0; kb < 2; ++kb) {
      int ko = kb*32 + qd*8;
      bf16x8 a0 = *(const bf16x8*)&As[wv*32 + l16][ko];
      bf16x8 a1 = *(const bf16x8*)&As[wv*32 + 16 + l16][ko];
#pragma unroll
      for (int ct = 0; ct < 4; ++ct) {
        bf16x8 b = *(const bf16x8*)&Bs[ct*16 + l16][ko];
        acc[0][ct] = __builtin_amdgcn_mfma_f32_16x16x32_bf16(a0, b, acc[0][ct], 0,0,0);
        acc[1][ct] = __builtin_amdgcn_mfma_f32_16x16x32_bf16(a1, b, acc[1][ct], 0,0,0);
      }
    }
    __syncthreads();
  }
  int three = j0 / 320;
  int rembase = j0 - three*320;
  if (three < 2) {
    ushort_t* dst = three == 0 ? q : k;
    float scale = three == 0 ? 0.125f : 1.0f;
#pragma unroll
    for (int rt = 0; rt < 2; ++rt)
#pragma unroll
      for (int ct = 0; ct < 4; ++ct) {
        int rem = rembase + ct*16 + l16;
        int h = rem >> 6, dd = rem & 63;
        float bi = bias[j0 + ct*16 + l16];
#pragma unroll
        for (int r = 0; r < 4; ++r) {
          int m = m0 + wv*32 + rt*16 + qd*4 + r;
          int b = m >> 10, n = m & (N_-1);
          dst[(((long)b*H_ + h)*N_ + n)*D_ + dd] = f2b((acc[rt][ct][r] + bi) * scale);
        }
      }
  } else {
    int h = rembase >> 6;
#pragma unroll
    for (int rt = 0; rt < 2; ++rt)
#pragma unroll
      for (int ct = 0; ct < 4; ++ct) {
        float bi = bias[j0 + ct*16 + l16];
#pragma unroll
        for (int r = 0; r < 4; ++r) {
          int col = wv*32 + rt*16 + qd*4 + r;
          Vs[ct*16 + l16][col] = f2b(acc[rt][ct][r] + bi);
        }
      }
    __syncthreads();
    int b = m0 >> 10, n0b = m0 & (N_-1);
#pragma unroll
    for (int i = 0; i < 4; ++i) {
      int idx = tid + 256*i;
      int row = idx >> 4, c8 = (idx & 15) << 3;
      *(uint4*)(vt + (((long)b*H_ + h)*D_ + row)*N_ + n0b + c8) = *(const uint4*)&Vs[row][c8];
    }
  }
}

// ---------------- QK^T per (b,h) via MFMA bf16: 128x128 tile / block ----------------
__global__ __launch_bounds__(256, 4) void qk_kernel(const ushort_t* __restrict__ q,
    const ushort_t* __restrict__ kmat, ushort_t* __restrict__ attn) {
  __shared__ __align__(16) ushort_t Qs[128][72];
  __shared__ __align__(16) ushort_t Ks[128][72];
  int bh = blockIdx.z;
  int m0 = blockIdx.x * 128;
  int n0 = blockIdx.y * 128;
  int tid = threadIdx.x;
  int lane = tid & 63, wv = tid >> 6;
  int l16 = lane & 15, qd = lane >> 4;
  const ushort_t* qb = q    + ((long)bh*N_ + m0)*D_;
  const ushort_t* kb = kmat + ((long)bh*N_ + n0)*D_;
#pragma unroll
  for (int i = 0; i < 4; ++i) {
    int chunk = tid + 256*i;
    int row = chunk >> 3, c8 = (chunk & 7) << 3;
    *(uint4*)&Qs[row][c8] = *(const uint4*)(qb + (long)row*D_ + c8);
    *(uint4*)&Ks[row][c8] = *(const uint4*)(kb + (long)row*D_ + c8);
  }
  __syncthreads();
  f32x4 acc[2][8];
#pragma unroll
  for (int i=0;i<2;++i)
#pragma unroll
    for (int j=0;j<8;++j) acc[i][j] = (f32x4){0.f,0.f,0.f,0.f};
#pragma unroll
  for (int ks = 0; ks < 2; ++ks) {
    int k0 = ks*32 + qd*8;
    bf16x8 a0 = *(const bf16x8*)&Qs[wv*32 + l16][k0];
    bf16x8 a1 = *(const bf16x8*)&Qs[wv*32 + 16 + l16][k0];
#pragma unroll
    for (int ct = 0; ct < 8; ++ct) {
      bf16x8 b = *(const bf16x8*)&Ks[ct*16 + l16][k0];
      acc[0][ct] = __builtin_amdgcn_mfma_f32_16x16x32_bf16(a0, b, acc[0][ct], 0,0,0);
      acc[1][ct] = __builtin_amdgcn_mfma_f32_16x16x32_bf16(a1, b, acc[1][ct], 0,0,0);
    }
  }
  ushort_t* ob = attn + ((long)bh*N_ + m0 + wv*32)*N_ + n0;
#pragma unroll
  for (int rt = 0; rt < 2; ++rt)
#pragma unroll
    for (int r = 0; r < 4; ++r) {
      long rowoff = (long)(rt*16 + qd*4 + r)*N_;
#pragma unroll
      for (int ct = 0; ct < 8; ++ct)
        ob[rowoff + ct*16 + l16] = f2b(acc[rt][ct][r]);
    }
}

// ------- Fused separable blur + softmax + MFMA PV (v5.1) -------
// v5 + stage-2 task split changed from rows {r, r+8} (14 ds_read_b128, 112
// unpacks) to adjacent pair {2o, 2o+1} with shared 8-row window (8 reads, 64
// unpacks, same 112 FMAs). Everything else identical to the 95.5 us v5.
#define CBS 1088
__global__ __launch_bounds__(1024) void bsp_kernel(
    const ushort_t* __restrict__ attn, const ushort_t* __restrict__ vt,
    ushort_t* __restrict__ aob) {
  __shared__ __align__(16) ushort_t raw[22][1024];   // halo rows; later PV partials
  __shared__ __align__(16) ushort_t cbP[16][CBS];    // col-blur (ghost gi=m+8) then P (swizzled)
  __shared__ float redm[16][2], reds[16][2], bsum[16];

  int bh = blockIdx.y;
  int h = bh % H_;
  int bb = bh / H_;
  int n0 = blockIdx.x * TM;
  int tid = threadIdx.x;
  int lane = tid & 63;
  const ushort_t* ab = attn + (long)bh*N_*N_;

  float sigma = (float)(h + 1);
  float ei = -1.f / (2.f * sigma * sigma);
  float ga = expf(9.f*ei), gb = expf(4.f*ei), gc = expf(1.f*ei);
  float isum = 1.f / (2.f*(ga + gb + gc) + 1.f);
  float alpha = 0.1f * sigma;
  float u0 = uni(ga*isum), u1 = uni(gb*isum), u2 = uni(gc*isum), u3 = uni(isum);
  float au0 = uni(alpha*u0), au1 = uni(alpha*u1), au2 = uni(alpha*u2), au3 = uni(alpha*u3);
  const float uw[7] = {u0, u1, u2, u3, u2, u1, u0};
  const float aw[7] = {au0, au1, au2, au3, au2, au1, au0};

  // ---- stage 1: load 22 halo rows (reflect) ----
#pragma unroll
  for (int i = 0; i < 3; ++i) {
    int c = tid + 1024*i;
    if (c < 2816) {
      int pr = c >> 7, c8 = (c & 127) << 3;
      int p = n0 - 3 + pr;
      int rr = p < 0 ? -p : (p > N_-1 ? 2*(N_-1)-p : p);
      *(uint4*)&raw[pr][c8] = *(const uint4*)(ab + (long)rr*N_ + c8);
    }
  }
  __syncthreads();

  // ---- stage 2: column blur, adjacent row-pair, shared 8-row window ----
  {
    int o = tid >> 7;
    int cg = tid & 127;
    int m0c = cg << 3;
    float v0[8] = {0.f,0.f,0.f,0.f,0.f,0.f,0.f,0.f};
    float v1[8] = {0.f,0.f,0.f,0.f,0.f,0.f,0.f,0.f};
#pragma unroll
    for (int kof = 0; kof < 8; ++kof) {
      uint4 rwv = *(const uint4*)&raw[2*o + kof][m0c];
      const ushort_t* rs = (const ushort_t*)&rwv;
      float xv[8];
#pragma unroll
      for (int j = 0; j < 8; ++j) xv[j] = b2f(rs[j]);
      if (kof < 7) {
        float w = uw[kof];
#pragma unroll
        for (int j = 0; j < 8; ++j) v0[j] += w * xv[j];
      }
      if (kof >= 1) {
        float w = uw[kof-1];
#pragma unroll
        for (int j = 0; j < 8; ++j) v1[j] += w * xv[j];
      }
    }
    ushort_t pk0[8], pk1[8];
#pragma unroll
    for (int j = 0; j < 8; ++j) { pk0[j] = f2b(v0[j]); pk1[j] = f2b(v1[j]); }
    int r0 = 2*o, r1 = 2*o + 1;
    *(uint4*)&cbP[r0][m0c + 8] = *(const uint4*)pk0;
    *(uint4*)&cbP[r1][m0c + 8] = *(const uint4*)pk1;
    if (cg == 0) {
      cbP[r0][7] = pk0[1]; cbP[r0][6] = pk0[2]; cbP[r0][5] = pk0[3];
      cbP[r1][7] = pk1[1]; cbP[r1][6] = pk1[2]; cbP[r1][5] = pk1[3];
    }
    if (cg == 127) {
      cbP[r0][1032] = pk0[6]; cbP[r0][1033] = pk0[5]; cbP[r0][1034] = pk0[4];
      cbP[r1][1032] = pk1[6]; cbP[r1][1033] = pk1[5]; cbP[r1][1034] = pk1[4];
    }
  }
  __syncthreads();

  // ---- stage 3: row blur + center -> 16 logits in registers ----
  int o = tid >> 7;
  int cg = tid & 127;
  int m0c = cg << 3;
  float lgA[8], lgB[8];
#pragma unroll
  for (int half = 0; half < 2; ++half) {
    int r = 2*o + half;
    ushort_t cs[24];
    *(uint4*)&cs[0]  = *(const uint4*)&cbP[r][m0c];
    *(uint4*)&cs[8]  = *(const uint4*)&cbP[r][m0c + 8];
    *(uint4*)&cs[16] = *(const uint4*)&cbP[r][m0c + 16];
    float cf[24];
#pragma unroll
    for (int j = 0; j < 24; ++j) cf[j] = b2f(cs[j]);
    uint4 rwv = *(const uint4*)&raw[r + 3][m0c];
    const ushort_t* rs = (const ushort_t*)&rwv;
    float* lg = half ? lgB : lgA;
#pragma unroll
    for (int j = 0; j < 8; ++j) {
      float s = b2f(rs[j]);
#pragma unroll
      for (int t = 0; t < 7; ++t) s += aw[t] * cf[5 + j + t];
      lg[j] = s;
    }
  }

  // ---- softmax ----
  float lmA = lgA[0], lmB = lgB[0];
#pragma unroll
  for (int j = 1; j < 8; ++j) { lmA = fmaxf(lmA, lgA[j]); lmB = fmaxf(lmB, lgB[j]); }
#pragma unroll
  for (int off2 = 32; off2 > 0; off2 >>= 1) {
    lmA = fmaxf(lmA, __shfl_xor(lmA, off2, 64));
    lmB = fmaxf(lmB, __shfl_xor(lmB, off2, 64));
  }
  int wv2 = (tid >> 6) & 1;
  if (lane == 0) { redm[2*o][wv2] = lmA; redm[2*o+1][wv2] = lmB; }
  __syncthreads();    // cbP (cb) reads done -> safe to overwrite as P
  float bmA = fmaxf(redm[2*o][0], redm[2*o][1]);
  float bmB = fmaxf(redm[2*o+1][0], redm[2*o+1][1]);
  float smA = 0.f, smB = 0.f;
  unsigned pkA[4], pkB[4];
#pragma unroll
  for (int jj = 0; jj < 4; ++jj) {
    float eA0 = __expf(lgA[2*jj]   - bmA);
    float eA1 = __expf(lgA[2*jj+1] - bmA);
    float eB0 = __expf(lgB[2*jj]   - bmB);
    float eB1 = __expf(lgB[2*jj+1] - bmB);
    smA += eA0 + eA1; smB += eB0 + eB1;
    pkA[jj] = (unsigned)f2b(eA0) | ((unsigned)f2b(eA1) << 16);
    pkB[jj] = (unsigned)f2b(eB0) | ((unsigned)f2b(eB1) << 16);
  }
  *(uint4*)&cbP[2*o][((cg + 2*o) & 127) << 3]     = make_uint4(pkA[0], pkA[1], pkA[2], pkA[3]);
  *(uint4*)&cbP[2*o+1][((cg + 2*o+1) & 127) << 3] = make_uint4(pkB[0], pkB[1], pkB[2], pkB[3]);
#pragma unroll
  for (int off2 = 32; off2 > 0; off2 >>= 1) {
    smA += __shfl_xor(smA, off2, 64);
    smB += __shfl_xor(smB, off2, 64);
  }
  if (lane == 0) { reds[2*o][wv2] = smA; reds[2*o+1][wv2] = smB; }
  __syncthreads();                        // P + reds visible
  if (tid < 16) bsum[tid] = reds[tid][0] + reds[tid][1];

  // ---- PV via MFMA: out[16][64] = P[16][1024] @ V[1024][64] ----
  int wv = tid >> 6;
  int dt = wv & 3, kc = wv >> 2;
  int qd = lane >> 4, l16 = lane & 15;
  f32x4 pvacc = {0.f, 0.f, 0.f, 0.f};
  const ushort_t* vtb = vt + ((long)bh*D_ + dt*16 + l16)*N_;
#pragma unroll
  for (int s = 0; s < 8; ++s) {
    int g = kc*32 + s*4 + qd;
    bf16x8 afrag = *(const bf16x8*)&cbP[l16][((g + l16) & 127) << 3];
    bf16x8 bfrag = *(const bf16x8*)(vtb + (g << 3));
    pvacc = __builtin_amdgcn_mfma_f32_16x16x32_bf16(afrag, bfrag, pvacc, 0, 0, 0);
  }
  float* pvscr = (float*)&raw[0][0];      // raw dead after stage 3
  if (kc > 0) {
    *(f32x4*)(pvscr + ((kc-1)*4 + dt)*256 + lane*4) = pvacc;
  }
  __syncthreads();                        // partials + bsum visible
  if (kc == 0) {
#pragma unroll
    for (int j = 0; j < 3; ++j) {
      f32x4 oth = *(const f32x4*)(pvscr + (j*4 + dt)*256 + lane*4);
      pvacc += oth;
    }
#pragma unroll
    for (int r = 0; r < 4; ++r) {
      int row = qd*4 + r;
      aob[((long)(bb*N_ + n0 + row))*C_ + h*64 + dt*16 + l16] = f2b(pvacc[r] / bsum[row]);
    }
  }
}

// ---------------- proj GEMM via MFMA bf16: 128(M)x64(N) tile ----------------
__global__ __launch_bounds__(256) void projm_kernel(const ushort_t* __restrict__ aob,
    const ushort_t* __restrict__ wpb, const float* __restrict__ bias,
    float* __restrict__ out) {
  __shared__ __align__(16) ushort_t As[128][72];
  __shared__ __align__(16) ushort_t Bs[64][72];
  int j0 = blockIdx.x * 64;
  int m0 = blockIdx.y * 128;
  int tid = threadIdx.x;
  int lane = tid & 63, wv = tid >> 6;
  int l16 = lane & 15, qd = lane >> 4;
  f32x4 acc[2][4];
#pragma unroll
  for (int i=0;i<2;++i)
#pragma unroll
    for (int j=0;j<4;++j) acc[i][j] = (f32x4){0.f,0.f,0.f,0.f};
  for (int kk = 0; kk < C_; kk += 64) {
#pragma unroll
    for (int i = 0; i < 4; ++i) {
      int idx = tid + 256*i;
      int row = idx >> 3, c8 = (idx & 7) << 3;
      *(uint4*)&As[row][c8] = *(const uint4*)(aob + (long)(m0+row)*C_ + kk + c8);
    }
    {
      int idx = tid;
      int row = idx >> 3, c8 = (idx & 7) << 3;
      *(uint4*)&Bs[row][c8] = *(const uint4*)(wpb + (long)(j0+row)*C_ + kk + c8);
      idx = tid + 256; row = idx >> 3; c8 = (idx & 7) << 3;
      *(uint4*)&Bs[row][c8] = *(const uint4*)(wpb + (long)(j0+row)*C_ + kk + c8);
    }
    __syncthreads();
#pragma unroll
    for (int kb = 0; kb < 2; ++kb) {
      int ko = kb*32 + qd*8;
      bf16x8 a0 = *(const bf16x8*)&As[wv*32 + l16][ko];
      bf16x8 a1 = *(const bf16x8*)&As[wv*32 + 16 + l16][ko];
#pragma unroll
      for (int ct = 0; ct < 4; ++ct) {
        bf16x8 b = *(const bf16x8*)&Bs[ct*16 + l16][ko];
        acc[0][ct] = __builtin_amdgcn_mfma_f32_16x16x32_bf16(a0, b, acc[0][ct], 0,0,0);
        acc[1][ct] = __builtin_amdgcn_mfma_f32_16x16x32_bf16(a1, b, acc[1][ct], 0,0,0);
      }
    }
    __syncthreads();
  }
#pragma unroll
  for (int rt = 0; rt < 2; ++rt)
#pragma unroll
    for (int ct = 0; ct < 4; ++ct) {
      float bi = bias[j0 + ct*16 + l16];
#pragma unroll
      for (int r = 0; r < 4; ++r) {
        int m = m0 + wv*32 + rt*16 + qd*4 + r;
        out[(long)m*C_ + j0 + ct*16 + l16] = acc[rt][ct][r] + bi;
      }
    }
}

extern "C" void kernel_launch(void* const* d_in, const int* in_sizes, int n_in,
                              void* d_out, int out_size, void* d_ws, size_t ws_size,
                              hipStream_t stream) {
  const float* x      = (const float*)d_in[0];
  const float* ln_g   = (const float*)d_in[1];
  const float* ln_b   = (const float*)d_in[2];
  const float* qkv_w  = (const float*)d_in[3];
  const float* qkv_b  = (const float*)d_in[4];
  const float* proj_w = (const float*)d_in[5];
  const float* proj_b = (const float*)d_in[6];
  float* out = (float*)d_out;

  char* ws = (char*)d_ws;
  const long sz_bhnd = (long)B_*H_*N_*D_;   // 2,621,440
  ushort_t* xnb  = (ushort_t*)ws;                   ws += (long)M_*C_*2;
  ushort_t* aob  = (ushort_t*)ws;                   ws += (long)M_*C_*2;
  ushort_t* q    = (ushort_t*)ws;                   ws += sz_bhnd*2;
  ushort_t* k    = (ushort_t*)ws;                   ws += sz_bhnd*2;
  ushort_t* vt   = (ushort_t*)ws;                   ws += sz_bhnd*2;
  ushort_t* wqb  = (ushort_t*)ws;                   ws += (long)3*C_*C_*2;
  ushort_t* wpb  = (ushort_t*)ws;                   ws += (long)C_*C_*2;
  ushort_t* attn = (ushort_t*)ws;                   // [bh][query][key], 84 MB

  prep_kernel<<<2248, 256, 0, stream>>>(qkv_w, proj_w, x, ln_g, ln_b, wqb, wpb, xnb);
  qkvm_kernel<<<dim3(15, 64), 256, 0, stream>>>(xnb, wqb, qkv_b, q, k, vt);
  qk_kernel<<<dim3(8, 8, B_*H_), 256, 0, stream>>>(q, k, attn);
  bsp_kernel<<<dim3(N_/TM, B_*H_), 1024, 0, stream>>>(attn, vt, aob);
  projm_kernel<<<dim3(5, 64), 256, 0, stream>>>(aob, wpb, proj_b, out);
}